// Round 6
// baseline (326.731 us; speedup 1.0000x reference)
//
#include <hip/hip_runtime.h>

#define NTOK 4096
#define NEXP 8
#define MAXTILES 104

typedef __attribute__((ext_vector_type(8))) short short8;
typedef __attribute__((ext_vector_type(4))) float f32x4;
typedef __attribute__((ext_vector_type(4))) unsigned int uint4v;
typedef __attribute__((ext_vector_type(2))) unsigned int uint2v;

__device__ __forceinline__ unsigned short f2bf(float f) {
  union { float f; unsigned u; } v; v.f = f;
  unsigned u = v.u;
  return (unsigned short)((u + 0x7FFFu + ((u >> 16) & 1u)) >> 16);
}

__device__ __forceinline__ void gll16(const void* g, void* l) {
  __builtin_amdgcn_global_load_lds((const __attribute__((address_space(1))) void*)g,
                                   (__attribute__((address_space(3))) void*)l, 16, 0, 0);
}

// ------------- fp32 (M,N) -> bf16 (N,M) transpose; 27 slices, contiguous bf16 dst -------------
__global__ __launch_bounds__(256) void cvt_t_all_k(
    const float* __restrict__ w1, const float* __restrict__ w3, const float* __restrict__ w2,
    const float* __restrict__ sw1, const float* __restrict__ sw3, const float* __restrict__ sw2,
    unsigned short* __restrict__ dst /* w1T base; 27 contiguous 1M-elem slices */) {
  __shared__ unsigned short tile[64][65];
  int z = blockIdx.z;
  const float* S;
  if (z < 8) S = w1 + (size_t)z * 1048576;
  else if (z < 16) S = w3 + (size_t)(z - 8) * 1048576;
  else if (z < 24) S = w2 + (size_t)(z - 16) * 1048576;
  else S = (z == 24) ? sw1 : (z == 25) ? sw3 : sw2;
  unsigned short* Dp = dst + (size_t)z * 1048576;
  int r0 = blockIdx.y * 64, c0 = blockIdx.x * 64;
  int t = threadIdx.x;
  int r = t >> 2, cb = (t & 3) * 16;
  const float* sp = S + (size_t)(r0 + r) * 1024 + c0 + cb;
  f32x4 v0 = ((const f32x4*)sp)[0], v1 = ((const f32x4*)sp)[1];
  f32x4 v2 = ((const f32x4*)sp)[2], v3 = ((const f32x4*)sp)[3];
#pragma unroll
  for (int j = 0; j < 4; ++j) {
    tile[r][cb + j] = f2bf(v0[j]);
    tile[r][cb + 4 + j] = f2bf(v1[j]);
    tile[r][cb + 8 + j] = f2bf(v2[j]);
    tile[r][cb + 12 + j] = f2bf(v3[j]);
  }
  __syncthreads();
  unsigned short* dp = Dp + (size_t)(c0 + r) * 1024 + r0 + cb;
  uint4v o0, o1;
#pragma unroll
  for (int j = 0; j < 4; ++j) {
    o0[j] = (unsigned)tile[cb + 2 * j][r] | ((unsigned)tile[cb + 2 * j + 1][r] << 16);
    o1[j] = (unsigned)tile[cb + 8 + 2 * j][r] | ((unsigned)tile[cb + 9 + 2 * j][r] << 16);
  }
  ((uint4v*)dp)[0] = o0;
  ((uint4v*)dp)[1] = o1;
}

// ---- router: one token per wave; ATOMIC-FREE — emits per-token records ----
__global__ __launch_bounds__(256) void router_k(
    const float* __restrict__ x, const float* __restrict__ wr, unsigned short* __restrict__ xb,
    int* __restrict__ rec, float* __restrict__ wts, float* __restrict__ probs,
    float* __restrict__ lsebuf) {
  int t = threadIdx.x, lane = t & 63, wv = t >> 6;
  int tok = blockIdx.x * 4 + wv;
  const f32x4* x4 = (const f32x4*)(x + (size_t)tok * 1024);
  f32x4 xv[4];
#pragma unroll
  for (int j = 0; j < 4; ++j) xv[j] = x4[j * 64 + lane];

  unsigned short* xo = xb + (size_t)tok * 1024;
#pragma unroll
  for (int j = 0; j < 4; ++j) {
    uint2v o;
    o[0] = (unsigned)f2bf(xv[j][0]) | ((unsigned)f2bf(xv[j][1]) << 16);
    o[1] = (unsigned)f2bf(xv[j][2]) | ((unsigned)f2bf(xv[j][3]) << 16);
    *(uint2v*)(xo + j * 256 + lane * 4) = o;
  }

  float acc[NEXP];
#pragma unroll
  for (int e = 0; e < NEXP; ++e) acc[e] = 0.f;
#pragma unroll
  for (int j = 0; j < 4; ++j) {
    int base = j * 256 + lane * 4;
#pragma unroll
    for (int c = 0; c < 4; ++c) {
      float xf = xv[j][c];
      const f32x4* wp = (const f32x4*)(wr + (size_t)(base + c) * NEXP);
      f32x4 w0 = wp[0], w1 = wp[1];
#pragma unroll
      for (int e = 0; e < 4; ++e) { acc[e] += xf * w0[e]; acc[4 + e] += xf * w1[e]; }
    }
  }
#pragma unroll
  for (int off = 32; off > 0; off >>= 1) {
#pragma unroll
    for (int e = 0; e < NEXP; ++e) acc[e] += __shfl_xor(acc[e], off);
  }

  float mx = acc[0];
#pragma unroll
  for (int e = 1; e < NEXP; ++e) mx = fmaxf(mx, acc[e]);
  float s = 0.f;
#pragma unroll
  for (int e = 0; e < NEXP; ++e) s += __expf(acc[e] - mx);
  float inv = 1.f / s;

  if (lane < NEXP) probs[(size_t)tok * NEXP + lane] = __expf(acc[lane] - mx) * inv;
  if (lane == 0) {
    int i0 = 0; float v0 = acc[0];
#pragma unroll
    for (int e = 1; e < NEXP; ++e) if (acc[e] > v0) { v0 = acc[e]; i0 = e; }
    int i1 = -1; float v1 = -3.4e38f;
#pragma unroll
    for (int e = 0; e < NEXP; ++e) if (e != i0 && acc[e] > v1) { v1 = acc[e]; i1 = e; }
    rec[tok] = i0 | (i1 << 8);
    wts[2 * tok] = __expf(v0 - mx) * inv;
    wts[2 * tok + 1] = __expf(v1 - mx) * inv;
    lsebuf[tok] = mx + __logf(s);
  }
}

// ---- build: per-expert lists via LDS local slots + 8 global atomics/block; aux reductions ----
__global__ __launch_bounds__(256) void build_k(
    const int* __restrict__ rec, const float* __restrict__ wts, const float* __restrict__ probs,
    const float* __restrict__ lsebuf,
    int* __restrict__ tlist, float* __restrict__ wlist,
    int* __restrict__ counts, float* __restrict__ probsum, float* __restrict__ zsum) {
  __shared__ int lcnt[NEXP];
  __shared__ int gbase[NEXP];
  __shared__ float wProb[4][NEXP];
  __shared__ float wZ[4];
  int t = threadIdx.x, lane = t & 63, wv = t >> 6;
  if (t < NEXP) lcnt[t] = 0;
  __syncthreads();

  int tok = blockIdx.x * 256 + t;
  int r = rec[tok];
  int i0 = r & 255, i1 = (r >> 8) & 255;
  float w0 = wts[2 * tok], w1 = wts[2 * tok + 1];
  int p0 = atomicAdd(&lcnt[i0], 1);
  int p1 = atomicAdd(&lcnt[i1], 1);

  f32x4 pr0 = ((const f32x4*)(probs + (size_t)tok * NEXP))[0];
  f32x4 pr1 = ((const f32x4*)(probs + (size_t)tok * NEXP))[1];
  float lv = lsebuf[tok];
  float z = lv * lv;
#pragma unroll
  for (int off = 32; off > 0; off >>= 1) {
#pragma unroll
    for (int c = 0; c < 4; ++c) {
      pr0[c] += __shfl_xor(pr0[c], off);
      pr1[c] += __shfl_xor(pr1[c], off);
    }
    z += __shfl_xor(z, off);
  }
  if (lane == 0) {
#pragma unroll
    for (int c = 0; c < 4; ++c) { wProb[wv][c] = pr0[c]; wProb[wv][4 + c] = pr1[c]; }
    wZ[wv] = z;
  }
  __syncthreads();

  if (t < NEXP) {
    gbase[t] = atomicAdd(&counts[t], lcnt[t]);
    atomicAdd(&probsum[t], wProb[0][t] + wProb[1][t] + wProb[2][t] + wProb[3][t]);
  }
  if (t == 0) atomicAdd(zsum, wZ[0] + wZ[1] + wZ[2] + wZ[3]);
  __syncthreads();

  int q0 = gbase[i0] + p0, q1 = gbase[i1] + p1;
  tlist[i0 * NTOK + q0] = tok;
  wlist[i0 * NTOK + q0] = w0;
  tlist[i1 * NTOK + q1] = tok;
  wlist[i1 * NTOK + q1] = w1;
}

// ---------------- scan: row bases + flat tile work-list (experts then shared) ----------------
__global__ void scan_k(const int* __restrict__ counts, int* __restrict__ ebase, int* __restrict__ tiles) {
  if (threadIdx.x == 0 && blockIdx.x == 0) {
    int a = 0, t = 0;
    for (int e = 0; e < NEXP; ++e) {
      ebase[e] = a;
      int nt = (counts[e] + 127) >> 7;
      for (int i = 0; i < nt; ++i) tiles[t++] = (e << 16) | i;
      a += nt * 128;
    }
    ebase[NEXP] = a;
    for (int i = 0; i < 32; ++i) tiles[t++] = (NEXP << 16) | i;
    ebase[NEXP + 1] = a + NTOK;
    while (t < MAXTILES) tiles[t++] = -1;
  }
}

// ---- GEMM1: 128x64 tile, BK=64, gathered x rows, dual B (w1/w3), silu(g)*u -> hbuf bf16 ----
// LDS 32KB/block; acc = 64 AGPR; 32 MFMA per barrier pair
__global__ __launch_bounds__(256, 3) void gemm1_k(
    const unsigned short* __restrict__ xb,
    const unsigned short* __restrict__ w1T, const unsigned short* __restrict__ w3T,
    const unsigned short* __restrict__ sw1T, const unsigned short* __restrict__ sw3T,
    unsigned short* __restrict__ hout,
    const int* __restrict__ tlist, const int* __restrict__ counts,
    const int* __restrict__ ebase, const int* __restrict__ tiles) {
  int td = tiles[blockIdx.y];
  if (td < 0) return;
  const int e = td >> 16;
  const int m0 = (td & 0xFFFF) << 7;
  const int n0 = blockIdx.x * 64;
  const bool sh = (e == NEXP);
  const int n_e = sh ? NTOK : counts[e];
  const int hb = ebase[e];
  const unsigned short* B1p = sh ? sw1T : w1T + (size_t)e * 1048576;
  const unsigned short* B3p = sh ? sw3T : w3T + (size_t)e * 1048576;
  const int* listp = tlist + e * NTOK;

  __shared__ unsigned short As[128 * 64], Bs1[64 * 64], Bs3[64 * 64];
  const int tid = threadIdx.x, lane = tid & 63, wv = tid >> 6;
  const int wrw = wv >> 1, wc = wv & 1, l16 = lane & 15, lq = lane >> 4;

  // A: 1024 chunks (row r=c>>3, kc=c&7), swizzled source chunk ks = kc ^ (r&7)
  const unsigned short* ga[4];
#pragma unroll
  for (int i = 0; i < 4; ++i) {
    int c = tid + i * 256;
    int r = c >> 3, ks = (c & 7) ^ (r & 7);
    int ar = m0 + r;
    int rowA = sh ? ar : (ar < n_e ? (listp[ar] & 0xFFFF) : 0);
    ga[i] = xb + (size_t)rowA * 1024 + ks * 8;
  }
  // B: 512 chunks each
  const unsigned short* gb[2];
  const unsigned short* gc[2];
#pragma unroll
  for (int i = 0; i < 2; ++i) {
    int c = tid + i * 256;
    int r = c >> 3, ks = (c & 7) ^ (r & 7);
    gb[i] = B1p + (size_t)(n0 + r) * 1024 + ks * 8;
    gc[i] = B3p + (size_t)(n0 + r) * 1024 + ks * 8;
  }
  unsigned short* lA[4];
#pragma unroll
  for (int i = 0; i < 4; ++i) lA[i] = As + i * 2048 + wv * 512;
  unsigned short* lB[2] = {Bs1 + wv * 512, Bs1 + 2048 + wv * 512};
  unsigned short* lC[2] = {Bs3 + wv * 512, Bs3 + 2048 + wv * 512};

  f32x4 accg[4][2], accu[4][2];
#pragma unroll
  for (int mi = 0; mi < 4; ++mi)
#pragma unroll
    for (int ni = 0; ni < 2; ++ni)
#pragma unroll
      for (int r = 0; r < 4; ++r) { accg[mi][ni][r] = 0.f; accu[mi][ni][r] = 0.f; }

  for (int k0 = 0; k0 < 1024; k0 += 64) {
#pragma unroll
    for (int i = 0; i < 4; ++i) { gll16(ga[i], lA[i]); ga[i] += 64; }
#pragma unroll
    for (int i = 0; i < 2; ++i) { gll16(gb[i], lB[i]); gb[i] += 64; gll16(gc[i], lC[i]); gc[i] += 64; }
    __syncthreads();
#pragma unroll
    for (int kh = 0; kh < 2; ++kh) {
      short8 af[4], b1f[2], b3f[2];
#pragma unroll
      for (int mi = 0; mi < 4; ++mi) {
        int R = wrw * 64 + mi * 16 + l16;
        int s = (kh * 4 + lq) ^ (R & 7);
        af[mi] = *(const short8*)&As[R * 64 + s * 8];
      }
#pragma unroll
      for (int ni = 0; ni < 2; ++ni) {
        int R = wc * 32 + ni * 16 + l16;
        int s = (kh * 4 + lq) ^ (R & 7);
        b1f[ni] = *(const short8*)&Bs1[R * 64 + s * 8];
        b3f[ni] = *(const short8*)&Bs3[R * 64 + s * 8];
      }
#pragma unroll
      for (int mi = 0; mi < 4; ++mi)
#pragma unroll
        for (int ni = 0; ni < 2; ++ni) {
          accg[mi][ni] = __builtin_amdgcn_mfma_f32_16x16x32_bf16(af[mi], b1f[ni], accg[mi][ni], 0, 0, 0);
          accu[mi][ni] = __builtin_amdgcn_mfma_f32_16x16x32_bf16(af[mi], b3f[ni], accu[mi][ni], 0, 0, 0);
        }
    }
    __syncthreads();
  }

#pragma unroll
  for (int mi = 0; mi < 4; ++mi)
#pragma unroll
    for (int ni = 0; ni < 2; ++ni) {
      int col = n0 + wc * 32 + ni * 16 + l16;
#pragma unroll
      for (int r = 0; r < 4; ++r) {
        int row = m0 + wrw * 64 + mi * 16 + lq * 4 + r;
        float g = accg[mi][ni][r], u = accu[mi][ni][r];
        float h = g / (1.f + __expf(-g)) * u;
        hout[(size_t)(hb + row) * 1024 + col] = (row < n_e) ? f2bf(h) : (unsigned short)0;
      }
    }
}

// ---- GEMM2: 128x128 tile, BK=64, hbuf rows, B=w2/sw2; atomicAdd scaled outputs into out ----
__global__ __launch_bounds__(256, 3) void gemm2_k(
    const unsigned short* __restrict__ hbuf,
    const unsigned short* __restrict__ w2T, const unsigned short* __restrict__ sw2T,
    float* __restrict__ out,
    const int* __restrict__ tlist, const float* __restrict__ wlist,
    const int* __restrict__ counts, const int* __restrict__ ebase, const int* __restrict__ tiles) {
  int td = tiles[blockIdx.y];
  if (td < 0) return;
  const int e = td >> 16;
  const int m0 = (td & 0xFFFF) << 7;
  const int n0 = blockIdx.x * 128;
  const bool sh = (e == NEXP);
  const int n_e = sh ? NTOK : counts[e];
  const int hb = ebase[e];
  const unsigned short* Bp = sh ? sw2T : w2T + (size_t)e * 1048576;
  const int* listp = tlist + e * NTOK;

  __shared__ unsigned short As[128 * 64], Bs[128 * 64];
  const int tid = threadIdx.x, lane = tid & 63, wv = tid >> 6;
  const int wrw = wv >> 1, wc = wv & 1, l16 = lane & 15, lq = lane >> 4;

  const unsigned short* ga[4];
  const unsigned short* gb[4];
#pragma unroll
  for (int i = 0; i < 4; ++i) {
    int c = tid + i * 256;
    int r = c >> 3, ks = (c & 7) ^ (r & 7);
    ga[i] = hbuf + (size_t)(hb + m0 + r) * 1024 + ks * 8;  // padded rows zero-filled
    gb[i] = Bp + (size_t)(n0 + r) * 1024 + ks * 8;
  }
  unsigned short* lA[4];
  unsigned short* lB[4];
#pragma unroll
  for (int i = 0; i < 4; ++i) {
    lA[i] = As + i * 2048 + wv * 512;
    lB[i] = Bs + i * 2048 + wv * 512;
  }

  f32x4 acc[4][4];
#pragma unroll
  for (int mi = 0; mi < 4; ++mi)
#pragma unroll
    for (int ni = 0; ni < 4; ++ni)
#pragma unroll
      for (int r = 0; r < 4; ++r) acc[mi][ni][r] = 0.f;

  for (int k0 = 0; k0 < 1024; k0 += 64) {
#pragma unroll
    for (int i = 0; i < 4; ++i) {
      gll16(ga[i], lA[i]); ga[i] += 64;
      gll16(gb[i], lB[i]); gb[i] += 64;
    }
    __syncthreads();
#pragma unroll
    for (int kh = 0; kh < 2; ++kh) {
      short8 af[4], bf[4];
#pragma unroll
      for (int mi = 0; mi < 4; ++mi) {
        int R = wrw * 64 + mi * 16 + l16;
        int s = (kh * 4 + lq) ^ (R & 7);
        af[mi] = *(const short8*)&As[R * 64 + s * 8];
      }
#pragma unroll
      for (int ni = 0; ni < 4; ++ni) {
        int R = wc * 64 + ni * 16 + l16;
        int s = (kh * 4 + lq) ^ (R & 7);
        bf[ni] = *(const short8*)&Bs[R * 64 + s * 8];
      }
#pragma unroll
      for (int mi = 0; mi < 4; ++mi)
#pragma unroll
        for (int ni = 0; ni < 4; ++ni)
          acc[mi][ni] = __builtin_amdgcn_mfma_f32_16x16x32_bf16(af[mi], bf[ni], acc[mi][ni], 0, 0, 0);
    }
    __syncthreads();
  }

#pragma unroll
  for (int mi = 0; mi < 4; ++mi)
#pragma unroll
    for (int r = 0; r < 4; ++r) {
      int row = m0 + wrw * 64 + mi * 16 + lq * 4 + r;
      if (sh) {
        float* yp = out + (size_t)row * 1024 + n0 + wc * 64 + l16;
#pragma unroll
        for (int ni = 0; ni < 4; ++ni) atomicAdd(&yp[ni * 16], acc[mi][ni][r] * (1.f / 3.f));
      } else if (row < n_e) {
        int tok = listp[row] & 0xFFFF;
        float wt = wlist[e * NTOK + row] * (2.f / 3.f);
        float* yp = out + (size_t)tok * 1024 + n0 + wc * 64 + l16;
#pragma unroll
        for (int ni = 0; ni < 4; ++ni) atomicAdd(&yp[ni * 16], wt * acc[mi][ni][r]);
      }
    }
}

__global__ void losses_k(const int* __restrict__ counts, const float* __restrict__ probsum,
                         const float* __restrict__ zsum, float* __restrict__ out) {
  if (threadIdx.x == 0 && blockIdx.x == 0) {
    float dot = 0.f;
    for (int e = 0; e < NEXP; ++e) dot += (float)counts[e] * probsum[e];
    out[0] = 6.103515625e-7f * dot;  // E*LB_W/(NUM_LAYERS*N*K)
    out[1] = zsum[0] * (0.001f / 4096.f);
  }
}

extern "C" void kernel_launch(void* const* d_in, const int* in_sizes, int n_in,
                              void* d_out, int out_size, void* d_ws, size_t ws_size,
                              hipStream_t stream) {
  const float* x   = (const float*)d_in[0];
  const float* wrt = (const float*)d_in[1];
  const float* w1  = (const float*)d_in[2];
  const float* w3  = (const float*)d_in[3];
  const float* w2  = (const float*)d_in[4];
  const float* sw1 = (const float*)d_in[5];
  const float* sw3 = (const float*)d_in[6];
  const float* sw2 = (const float*)d_in[7];
  float* out = (float*)d_out;

  char* p = (char*)d_ws;
  auto alloc = [&](size_t b) { char* r = p; p += (b + 255) & ~(size_t)255; return r; };
  unsigned short* xb   = (unsigned short*)alloc((size_t)NTOK * 1024 * 2);
  unsigned short* w1T  = (unsigned short*)alloc((size_t)27 * 1048576 * 2);
  unsigned short* w3T  = w1T + (size_t)8 * 1048576;
  unsigned short* w2T  = w3T + (size_t)8 * 1048576;
  unsigned short* sw1T = w2T + (size_t)8 * 1048576;
  unsigned short* sw3T = sw1T + 1048576;
  unsigned short* sw2T = sw3T + 1048576;
  unsigned short* hbuf = (unsigned short*)alloc((size_t)13312 * 1024 * 2);
  int* tlist    = (int*)alloc((size_t)NEXP * NTOK * 4);
  float* wlist  = (float*)alloc((size_t)NEXP * NTOK * 4);
  int* rec      = (int*)alloc((size_t)NTOK * 4);
  float* wts    = (float*)alloc((size_t)NTOK * 2 * 4);
  float* probs  = (float*)alloc((size_t)NTOK * NEXP * 4);
  float* lsebuf = (float*)alloc((size_t)NTOK * 4);
  int* tiles    = (int*)alloc(MAXTILES * 4);
  int* ebase    = (int*)alloc(256);
  char* stats   = alloc(768);
  int* counts   = (int*)stats;
  float* probsum = (float*)(stats + 256);
  float* zsum    = (float*)(stats + 512);

  (void)hipMemsetAsync(stats, 0, 768, stream);
  (void)hipMemsetAsync(out, 0, (size_t)out_size * 4, stream);

  cvt_t_all_k<<<dim3(16, 16, 27), 256, 0, stream>>>(w1, w3, w2, sw1, sw3, sw2, w1T);
  router_k<<<1024, 256, 0, stream>>>(x, wrt, xb, rec, wts, probs, lsebuf);
  build_k<<<16, 256, 0, stream>>>(rec, wts, probs, lsebuf, tlist, wlist, counts, probsum, zsum);
  scan_k<<<1, 64, 0, stream>>>(counts, ebase, tiles);
  gemm1_k<<<dim3(16, MAXTILES), 256, 0, stream>>>(xb, w1T, w3T, sw1T, sw3T, hbuf, tlist, counts, ebase, tiles);
  gemm2_k<<<dim3(8, MAXTILES), 256, 0, stream>>>(hbuf, w2T, sw2T, out, tlist, wlist, counts, ebase, tiles);
  losses_k<<<1, 64, 0, stream>>>(counts, probsum, zsum, out + (size_t)NTOK * 1024);
}

// Round 7
// 315.814 us; speedup vs baseline: 1.0346x; 1.0346x over previous
//
#include <hip/hip_runtime.h>

#define NTOK 4096
#define NEXP 8
#define MAXTILES 104

typedef __attribute__((ext_vector_type(8))) short short8;
typedef __attribute__((ext_vector_type(4))) float f32x4;
typedef __attribute__((ext_vector_type(4))) unsigned int uint4v;
typedef __attribute__((ext_vector_type(2))) unsigned int uint2v;

__device__ __forceinline__ unsigned short f2bf(float f) {
  union { float f; unsigned u; } v; v.f = f;
  unsigned u = v.u;
  return (unsigned short)((u + 0x7FFFu + ((u >> 16) & 1u)) >> 16);
}

__device__ __forceinline__ void gll16(const void* g, void* l) {
  __builtin_amdgcn_global_load_lds((const __attribute__((address_space(1))) void*)g,
                                   (__attribute__((address_space(3))) void*)l, 16, 0, 0);
}

// ---- fused prep: blocks [0,6912) = weight fp32->bf16 transpose; [6912,7936) = router ----
__global__ __launch_bounds__(256) void prep_k(
    const float* __restrict__ w1, const float* __restrict__ w3, const float* __restrict__ w2,
    const float* __restrict__ sw1, const float* __restrict__ sw3, const float* __restrict__ sw2,
    unsigned short* __restrict__ dst,
    const float* __restrict__ x, const float* __restrict__ wr, unsigned short* __restrict__ xb,
    int* __restrict__ rec, float* __restrict__ wts, float* __restrict__ probs,
    float* __restrict__ lsebuf) {
  __shared__ unsigned short tile[64][65];
  int b = blockIdx.x;
  if (b < 6912) {
    int z = b >> 8, rem = b & 255;
    int r0 = (rem >> 4) * 64, c0 = (rem & 15) * 64;
    const float* S;
    if (z < 8) S = w1 + (size_t)z * 1048576;
    else if (z < 16) S = w3 + (size_t)(z - 8) * 1048576;
    else if (z < 24) S = w2 + (size_t)(z - 16) * 1048576;
    else S = (z == 24) ? sw1 : (z == 25) ? sw3 : sw2;
    unsigned short* Dp = dst + (size_t)z * 1048576;
    int t = threadIdx.x;
    int r = t >> 2, cb = (t & 3) * 16;
    const float* sp = S + (size_t)(r0 + r) * 1024 + c0 + cb;
    f32x4 v0 = ((const f32x4*)sp)[0], v1 = ((const f32x4*)sp)[1];
    f32x4 v2 = ((const f32x4*)sp)[2], v3 = ((const f32x4*)sp)[3];
#pragma unroll
    for (int j = 0; j < 4; ++j) {
      tile[r][cb + j] = f2bf(v0[j]);
      tile[r][cb + 4 + j] = f2bf(v1[j]);
      tile[r][cb + 8 + j] = f2bf(v2[j]);
      tile[r][cb + 12 + j] = f2bf(v3[j]);
    }
    __syncthreads();
    unsigned short* dp = Dp + (size_t)(c0 + r) * 1024 + r0 + cb;
    uint4v o0, o1;
#pragma unroll
    for (int j = 0; j < 4; ++j) {
      o0[j] = (unsigned)tile[cb + 2 * j][r] | ((unsigned)tile[cb + 2 * j + 1][r] << 16);
      o1[j] = (unsigned)tile[cb + 8 + 2 * j][r] | ((unsigned)tile[cb + 9 + 2 * j][r] << 16);
    }
    ((uint4v*)dp)[0] = o0;
    ((uint4v*)dp)[1] = o1;
  } else {
    int t = threadIdx.x, lane = t & 63, wv = t >> 6;
    int tok = (b - 6912) * 4 + wv;
    const f32x4* x4 = (const f32x4*)(x + (size_t)tok * 1024);
    f32x4 xv[4];
#pragma unroll
    for (int j = 0; j < 4; ++j) xv[j] = x4[j * 64 + lane];

    unsigned short* xo = xb + (size_t)tok * 1024;
#pragma unroll
    for (int j = 0; j < 4; ++j) {
      uint2v o;
      o[0] = (unsigned)f2bf(xv[j][0]) | ((unsigned)f2bf(xv[j][1]) << 16);
      o[1] = (unsigned)f2bf(xv[j][2]) | ((unsigned)f2bf(xv[j][3]) << 16);
      *(uint2v*)(xo + j * 256 + lane * 4) = o;
    }

    float acc[NEXP];
#pragma unroll
    for (int e = 0; e < NEXP; ++e) acc[e] = 0.f;
#pragma unroll
    for (int j = 0; j < 4; ++j) {
      int base = j * 256 + lane * 4;
#pragma unroll
      for (int c = 0; c < 4; ++c) {
        float xf = xv[j][c];
        const f32x4* wp = (const f32x4*)(wr + (size_t)(base + c) * NEXP);
        f32x4 q0 = wp[0], q1 = wp[1];
#pragma unroll
        for (int e = 0; e < 4; ++e) { acc[e] += xf * q0[e]; acc[4 + e] += xf * q1[e]; }
      }
    }
#pragma unroll
    for (int off = 32; off > 0; off >>= 1) {
#pragma unroll
      for (int e = 0; e < NEXP; ++e) acc[e] += __shfl_xor(acc[e], off);
    }

    float mx = acc[0];
#pragma unroll
    for (int e = 1; e < NEXP; ++e) mx = fmaxf(mx, acc[e]);
    float s = 0.f;
#pragma unroll
    for (int e = 0; e < NEXP; ++e) s += __expf(acc[e] - mx);
    float inv = 1.f / s;

    if (lane < NEXP) probs[(size_t)tok * NEXP + lane] = __expf(acc[lane] - mx) * inv;
    if (lane == 0) {
      int i0 = 0; float v0 = acc[0];
#pragma unroll
      for (int e = 1; e < NEXP; ++e) if (acc[e] > v0) { v0 = acc[e]; i0 = e; }
      int i1 = -1; float v1 = -3.4e38f;
#pragma unroll
      for (int e = 0; e < NEXP; ++e) if (e != i0 && acc[e] > v1) { v1 = acc[e]; i1 = e; }
      rec[tok] = i0 | (i1 << 8);
      wts[2 * tok] = __expf(v0 - mx) * inv;
      wts[2 * tok + 1] = __expf(v1 - mx) * inv;
      lsebuf[tok] = mx + __logf(s);
    }
  }
}

// ---- build: SINGLE block — lists via LDS counters, ebase/tiles/counts/losses all here ----
__global__ __launch_bounds__(1024) void build_k(
    const int* __restrict__ rec, const float* __restrict__ wts, const float* __restrict__ probs,
    const float* __restrict__ lsebuf,
    int* __restrict__ tlist, float* __restrict__ wlist,
    int* __restrict__ counts, int* __restrict__ ebase, int* __restrict__ tiles,
    float* __restrict__ lossout) {
  __shared__ int lcnt[NEXP];
  __shared__ float sprob[NEXP];
  __shared__ float sz;
  int t = threadIdx.x, lane = t & 63;
  if (t < NEXP) { lcnt[t] = 0; sprob[t] = 0.f; }
  if (t == 0) sz = 0.f;
  __syncthreads();

  float pacc[NEXP];
#pragma unroll
  for (int e = 0; e < NEXP; ++e) pacc[e] = 0.f;
  float zacc = 0.f;

#pragma unroll
  for (int it = 0; it < 4; ++it) {
    int tok = t + it * 1024;
    int r = rec[tok];
    int i0 = r & 255, i1 = (r >> 8) & 255;
    int p0 = atomicAdd(&lcnt[i0], 1);
    tlist[i0 * NTOK + p0] = tok;
    wlist[i0 * NTOK + p0] = wts[2 * tok];
    int p1 = atomicAdd(&lcnt[i1], 1);
    tlist[i1 * NTOK + p1] = tok | (1 << 16);
    wlist[i1 * NTOK + p1] = wts[2 * tok + 1];
    f32x4 a = ((const f32x4*)(probs + (size_t)tok * NEXP))[0];
    f32x4 c = ((const f32x4*)(probs + (size_t)tok * NEXP))[1];
#pragma unroll
    for (int j = 0; j < 4; ++j) { pacc[j] += a[j]; pacc[4 + j] += c[j]; }
    float lv = lsebuf[tok];
    zacc += lv * lv;
  }
#pragma unroll
  for (int off = 32; off > 0; off >>= 1) {
#pragma unroll
    for (int e = 0; e < NEXP; ++e) pacc[e] += __shfl_xor(pacc[e], off);
    zacc += __shfl_xor(zacc, off);
  }
  if (lane == 0) {
#pragma unroll
    for (int e = 0; e < NEXP; ++e) atomicAdd(&sprob[e], pacc[e]);
    atomicAdd(&sz, zacc);
  }
  __syncthreads();

  if (t == 0) {
    int a = 0, tt = 0;
    float dot = 0.f;
    for (int e = 0; e < NEXP; ++e) {
      counts[e] = lcnt[e];
      ebase[e] = a;
      int nt = (lcnt[e] + 127) >> 7;
      for (int i = 0; i < nt; ++i) tiles[tt++] = (e << 16) | i;
      a += nt * 128;
      dot += (float)lcnt[e] * sprob[e];
    }
    ebase[NEXP] = a;
    for (int i = 0; i < 32; ++i) tiles[tt++] = (NEXP << 16) | i;
    while (tt < MAXTILES) tiles[tt++] = -1;
    lossout[0] = 6.103515625e-7f * dot;  // E*LB_W/(NUM_LAYERS*N*K)
    lossout[1] = sz * (0.001f / 4096.f);
  }
}

// ---- GEMM1: 128x64 tile, BK=64, gathered x rows, dual B (w1/w3), silu(g)*u -> hbuf bf16 ----
__global__ __launch_bounds__(256, 3) void gemm1_k(
    const unsigned short* __restrict__ xb,
    const unsigned short* __restrict__ w1T, const unsigned short* __restrict__ w3T,
    const unsigned short* __restrict__ sw1T, const unsigned short* __restrict__ sw3T,
    unsigned short* __restrict__ hout,
    const int* __restrict__ tlist, const int* __restrict__ counts,
    const int* __restrict__ ebase, const int* __restrict__ tiles) {
  int td = tiles[blockIdx.y];
  if (td < 0) return;
  const int e = td >> 16;
  const int m0 = (td & 0xFFFF) << 7;
  const int n0 = blockIdx.x * 64;
  const bool sh = (e == NEXP);
  const int n_e = sh ? NTOK : counts[e];
  const int hb = ebase[e];
  const unsigned short* B1p = sh ? sw1T : w1T + (size_t)e * 1048576;
  const unsigned short* B3p = sh ? sw3T : w3T + (size_t)e * 1048576;
  const int* listp = tlist + e * NTOK;

  __shared__ unsigned short As[128 * 64], Bs1[64 * 64], Bs3[64 * 64];
  const int tid = threadIdx.x, lane = tid & 63, wv = tid >> 6;
  const int wrw = wv >> 1, wc = wv & 1, l16 = lane & 15, lq = lane >> 4;

  const unsigned short* ga[4];
#pragma unroll
  for (int i = 0; i < 4; ++i) {
    int c = tid + i * 256;
    int r = c >> 3, ks = (c & 7) ^ (r & 7);
    int ar = m0 + r;
    int rowA = sh ? ar : (ar < n_e ? (listp[ar] & 0xFFFF) : 0);
    ga[i] = xb + (size_t)rowA * 1024 + ks * 8;
  }
  const unsigned short* gb[2];
  const unsigned short* gc[2];
#pragma unroll
  for (int i = 0; i < 2; ++i) {
    int c = tid + i * 256;
    int r = c >> 3, ks = (c & 7) ^ (r & 7);
    gb[i] = B1p + (size_t)(n0 + r) * 1024 + ks * 8;
    gc[i] = B3p + (size_t)(n0 + r) * 1024 + ks * 8;
  }
  unsigned short* lA[4];
#pragma unroll
  for (int i = 0; i < 4; ++i) lA[i] = As + i * 2048 + wv * 512;
  unsigned short* lB[2] = {Bs1 + wv * 512, Bs1 + 2048 + wv * 512};
  unsigned short* lC[2] = {Bs3 + wv * 512, Bs3 + 2048 + wv * 512};

  f32x4 accg[4][2], accu[4][2];
#pragma unroll
  for (int mi = 0; mi < 4; ++mi)
#pragma unroll
    for (int ni = 0; ni < 2; ++ni)
#pragma unroll
      for (int r = 0; r < 4; ++r) { accg[mi][ni][r] = 0.f; accu[mi][ni][r] = 0.f; }

  for (int k0 = 0; k0 < 1024; k0 += 64) {
#pragma unroll
    for (int i = 0; i < 4; ++i) { gll16(ga[i], lA[i]); ga[i] += 64; }
#pragma unroll
    for (int i = 0; i < 2; ++i) { gll16(gb[i], lB[i]); gb[i] += 64; gll16(gc[i], lC[i]); gc[i] += 64; }
    __syncthreads();
#pragma unroll
    for (int kh = 0; kh < 2; ++kh) {
      short8 af[4], b1f[2], b3f[2];
#pragma unroll
      for (int mi = 0; mi < 4; ++mi) {
        int R = wrw * 64 + mi * 16 + l16;
        int s = (kh * 4 + lq) ^ (R & 7);
        af[mi] = *(const short8*)&As[R * 64 + s * 8];
      }
#pragma unroll
      for (int ni = 0; ni < 2; ++ni) {
        int R = wc * 32 + ni * 16 + l16;
        int s = (kh * 4 + lq) ^ (R & 7);
        b1f[ni] = *(const short8*)&Bs1[R * 64 + s * 8];
        b3f[ni] = *(const short8*)&Bs3[R * 64 + s * 8];
      }
#pragma unroll
      for (int mi = 0; mi < 4; ++mi)
#pragma unroll
        for (int ni = 0; ni < 2; ++ni) {
          accg[mi][ni] = __builtin_amdgcn_mfma_f32_16x16x32_bf16(af[mi], b1f[ni], accg[mi][ni], 0, 0, 0);
          accu[mi][ni] = __builtin_amdgcn_mfma_f32_16x16x32_bf16(af[mi], b3f[ni], accu[mi][ni], 0, 0, 0);
        }
    }
    __syncthreads();
  }

#pragma unroll
  for (int mi = 0; mi < 4; ++mi)
#pragma unroll
    for (int ni = 0; ni < 2; ++ni) {
      int col = n0 + wc * 32 + ni * 16 + l16;
#pragma unroll
      for (int r = 0; r < 4; ++r) {
        int row = m0 + wrw * 64 + mi * 16 + lq * 4 + r;
        float g = accg[mi][ni][r], u = accu[mi][ni][r];
        float h = g / (1.f + __expf(-g)) * u;
        hout[(size_t)(hb + row) * 1024 + col] = (row < n_e) ? f2bf(h) : (unsigned short)0;
      }
    }
}

// ---- GEMM2: 128x128 tile, BK=64; streaming stores of scaled outputs into ybuf slices ----
__global__ __launch_bounds__(256, 3) void gemm2_k(
    const unsigned short* __restrict__ hbuf,
    const unsigned short* __restrict__ w2T, const unsigned short* __restrict__ sw2T,
    float* __restrict__ yout,
    const int* __restrict__ tlist, const float* __restrict__ wlist,
    const int* __restrict__ counts, const int* __restrict__ ebase, const int* __restrict__ tiles) {
  int td = tiles[blockIdx.y];
  if (td < 0) return;
  const int e = td >> 16;
  const int m0 = (td & 0xFFFF) << 7;
  const int n0 = blockIdx.x * 128;
  const bool sh = (e == NEXP);
  const int n_e = sh ? NTOK : counts[e];
  const int hb = ebase[e];
  const unsigned short* Bp = sh ? sw2T : w2T + (size_t)e * 1048576;
  const int* listp = tlist + e * NTOK;

  __shared__ unsigned short As[128 * 64], Bs[128 * 64];
  const int tid = threadIdx.x, lane = tid & 63, wv = tid >> 6;
  const int wrw = wv >> 1, wc = wv & 1, l16 = lane & 15, lq = lane >> 4;

  const unsigned short* ga[4];
  const unsigned short* gb[4];
#pragma unroll
  for (int i = 0; i < 4; ++i) {
    int c = tid + i * 256;
    int r = c >> 3, ks = (c & 7) ^ (r & 7);
    ga[i] = hbuf + (size_t)(hb + m0 + r) * 1024 + ks * 8;  // padded rows zero-filled
    gb[i] = Bp + (size_t)(n0 + r) * 1024 + ks * 8;
  }
  unsigned short* lA[4];
  unsigned short* lB[4];
#pragma unroll
  for (int i = 0; i < 4; ++i) {
    lA[i] = As + i * 2048 + wv * 512;
    lB[i] = Bs + i * 2048 + wv * 512;
  }

  f32x4 acc[4][4];
#pragma unroll
  for (int mi = 0; mi < 4; ++mi)
#pragma unroll
    for (int ni = 0; ni < 4; ++ni)
#pragma unroll
      for (int r = 0; r < 4; ++r) acc[mi][ni][r] = 0.f;

  for (int k0 = 0; k0 < 1024; k0 += 64) {
#pragma unroll
    for (int i = 0; i < 4; ++i) {
      gll16(ga[i], lA[i]); ga[i] += 64;
      gll16(gb[i], lB[i]); gb[i] += 64;
    }
    __syncthreads();
#pragma unroll
    for (int kh = 0; kh < 2; ++kh) {
      short8 af[4], bf[4];
#pragma unroll
      for (int mi = 0; mi < 4; ++mi) {
        int R = wrw * 64 + mi * 16 + l16;
        int s = (kh * 4 + lq) ^ (R & 7);
        af[mi] = *(const short8*)&As[R * 64 + s * 8];
      }
#pragma unroll
      for (int ni = 0; ni < 4; ++ni) {
        int R = wc * 64 + ni * 16 + l16;
        int s = (kh * 4 + lq) ^ (R & 7);
        bf[ni] = *(const short8*)&Bs[R * 64 + s * 8];
      }
#pragma unroll
      for (int mi = 0; mi < 4; ++mi)
#pragma unroll
        for (int ni = 0; ni < 4; ++ni)
          acc[mi][ni] = __builtin_amdgcn_mfma_f32_16x16x32_bf16(af[mi], bf[ni], acc[mi][ni], 0, 0, 0);
    }
    __syncthreads();
  }

#pragma unroll
  for (int mi = 0; mi < 4; ++mi)
#pragma unroll
    for (int r = 0; r < 4; ++r) {
      int row = m0 + wrw * 64 + mi * 16 + lq * 4 + r;
      if (sh) {
        float* yp = yout + ((size_t)2 * NTOK + row) * 1024 + n0 + wc * 64 + l16;
#pragma unroll
        for (int ni = 0; ni < 4; ++ni) yp[ni * 16] = acc[mi][ni][r] * (1.f / 3.f);
      } else if (row < n_e) {
        int ent = listp[row];
        float wt = wlist[e * NTOK + row] * (2.f / 3.f);
        int tok = ent & 0xFFFF, ks = ent >> 16;
        float* yp = yout + ((size_t)ks * NTOK + tok) * 1024 + n0 + wc * 64 + l16;
#pragma unroll
        for (int ni = 0; ni < 4; ++ni) yp[ni * 16] = wt * acc[mi][ni][r];
      }
    }
}

// ---------------- combine: out = y0 + y1 + y2 (scales folded in gemm2) ----------------
__global__ __launch_bounds__(256) void combine_k(const float* __restrict__ y,
                                                 float* __restrict__ out) {
  size_t i = (size_t)blockIdx.x * 256 + threadIdx.x;
  const f32x4* y0 = (const f32x4*)y + i;
  const f32x4* y1 = y0 + (NTOK * 1024 / 4);
  const f32x4* y2 = y1 + (NTOK * 1024 / 4);
  ((f32x4*)out)[i] = *y0 + *y1 + *y2;
}

extern "C" void kernel_launch(void* const* d_in, const int* in_sizes, int n_in,
                              void* d_out, int out_size, void* d_ws, size_t ws_size,
                              hipStream_t stream) {
  const float* x   = (const float*)d_in[0];
  const float* wrt = (const float*)d_in[1];
  const float* w1  = (const float*)d_in[2];
  const float* w3  = (const float*)d_in[3];
  const float* w2  = (const float*)d_in[4];
  const float* sw1 = (const float*)d_in[5];
  const float* sw3 = (const float*)d_in[6];
  const float* sw2 = (const float*)d_in[7];
  float* out = (float*)d_out;

  char* p = (char*)d_ws;
  auto alloc = [&](size_t b) { char* r = p; p += (b + 255) & ~(size_t)255; return r; };
  unsigned short* xb   = (unsigned short*)alloc((size_t)NTOK * 1024 * 2);
  unsigned short* w1T  = (unsigned short*)alloc((size_t)27 * 1048576 * 2);
  unsigned short* w3T  = w1T + (size_t)8 * 1048576;
  unsigned short* w2T  = w3T + (size_t)8 * 1048576;
  unsigned short* sw1T = w2T + (size_t)8 * 1048576;
  unsigned short* sw3T = sw1T + 1048576;
  unsigned short* sw2T = sw3T + 1048576;
  unsigned short* hbuf = (unsigned short*)alloc((size_t)13312 * 1024 * 2);
  float* ybuf   = (float*)alloc((size_t)3 * NTOK * 1024 * 4);
  int* tlist    = (int*)alloc((size_t)NEXP * NTOK * 4);
  float* wlist  = (float*)alloc((size_t)NEXP * NTOK * 4);
  int* rec      = (int*)alloc((size_t)NTOK * 4);
  float* wts    = (float*)alloc((size_t)NTOK * 2 * 4);
  float* probs  = (float*)alloc((size_t)NTOK * NEXP * 4);
  float* lsebuf = (float*)alloc((size_t)NTOK * 4);
  int* tiles    = (int*)alloc(MAXTILES * 4);
  int* ebase    = (int*)alloc(256);
  int* counts   = (int*)alloc(256);

  prep_k<<<7936, 256, 0, stream>>>(w1, w3, w2, sw1, sw3, sw2, w1T,
                                   x, wrt, xb, rec, wts, probs, lsebuf);
  build_k<<<1, 1024, 0, stream>>>(rec, wts, probs, lsebuf, tlist, wlist,
                                  counts, ebase, tiles, out + (size_t)NTOK * 1024);
  gemm1_k<<<dim3(16, MAXTILES), 256, 0, stream>>>(xb, w1T, w3T, sw1T, sw3T, hbuf, tlist, counts, ebase, tiles);
  gemm2_k<<<dim3(8, MAXTILES), 256, 0, stream>>>(hbuf, w2T, sw2T, ybuf, tlist, wlist, counts, ebase, tiles);
  combine_k<<<NTOK * 1024 / 4 / 256, 256, 0, stream>>>(ybuf, out);
}

// Round 8
// 303.769 us; speedup vs baseline: 1.0756x; 1.0397x over previous
//
#include <hip/hip_runtime.h>

#define NTOK 4096
#define NEXP 8
#define MAXTILES 104

typedef __attribute__((ext_vector_type(8))) short short8;
typedef __attribute__((ext_vector_type(4))) float f32x4;
typedef __attribute__((ext_vector_type(4))) unsigned int uint4v;
typedef __attribute__((ext_vector_type(2))) unsigned int uint2v;

__device__ __forceinline__ unsigned short f2bf(float f) {
  union { float f; unsigned u; } v; v.f = f;
  unsigned u = v.u;
  return (unsigned short)((u + 0x7FFFu + ((u >> 16) & 1u)) >> 16);
}

__device__ __forceinline__ void gll16(const void* g, void* l) {
  __builtin_amdgcn_global_load_lds((const __attribute__((address_space(1))) void*)g,
                                   (__attribute__((address_space(3))) void*)l, 16, 0, 0);
}

// shared 64x64 fp32->bf16 transpose tile body (proven: 0 bank conflicts)
__device__ __forceinline__ void transpose_tile(const float* __restrict__ S,
                                               unsigned short* __restrict__ Dp,
                                               int r0, int c0, int t,
                                               unsigned short (*tile)[65]) {
  int r = t >> 2, cb = (t & 3) * 16;
  const float* sp = S + (size_t)(r0 + r) * 1024 + c0 + cb;
  f32x4 v0 = ((const f32x4*)sp)[0], v1 = ((const f32x4*)sp)[1];
  f32x4 v2 = ((const f32x4*)sp)[2], v3 = ((const f32x4*)sp)[3];
#pragma unroll
  for (int j = 0; j < 4; ++j) {
    tile[r][cb + j] = f2bf(v0[j]);
    tile[r][cb + 4 + j] = f2bf(v1[j]);
    tile[r][cb + 8 + j] = f2bf(v2[j]);
    tile[r][cb + 12 + j] = f2bf(v3[j]);
  }
  __syncthreads();
  unsigned short* dp = Dp + (size_t)(c0 + r) * 1024 + r0 + cb;
  uint4v o0, o1;
#pragma unroll
  for (int j = 0; j < 4; ++j) {
    o0[j] = (unsigned)tile[cb + 2 * j][r] | ((unsigned)tile[cb + 2 * j + 1][r] << 16);
    o1[j] = (unsigned)tile[cb + 8 + 2 * j][r] | ((unsigned)tile[cb + 9 + 2 * j][r] << 16);
  }
  ((uint4v*)dp)[0] = o0;
  ((uint4v*)dp)[1] = o1;
}

// ---- prep: blocks [0,4608) = w1/w3/sw1/sw3 transpose (18 slices); [4608,5632) = router ----
__global__ __launch_bounds__(256) void prep_k(
    const float* __restrict__ w1, const float* __restrict__ w3,
    const float* __restrict__ sw1, const float* __restrict__ sw3,
    unsigned short* __restrict__ dst /* w1T base */,
    const float* __restrict__ x, const float* __restrict__ wr, unsigned short* __restrict__ xb,
    int* __restrict__ rec, float* __restrict__ wts, float* __restrict__ probs,
    float* __restrict__ lsebuf) {
  __shared__ unsigned short tile[64][65];
  int b = blockIdx.x;
  if (b < 4608) {
    int z = b >> 8, rem = b & 255;
    const float* S;
    unsigned short* Dp;
    if (z < 8) { S = w1 + (size_t)z * 1048576; Dp = dst + (size_t)z * 1048576; }
    else if (z < 16) { S = w3 + (size_t)(z - 8) * 1048576; Dp = dst + (size_t)z * 1048576; }
    else if (z == 16) { S = sw1; Dp = dst + (size_t)24 * 1048576; }
    else { S = sw3; Dp = dst + (size_t)25 * 1048576; }
    transpose_tile(S, Dp, (rem >> 4) * 64, (rem & 15) * 64, threadIdx.x, tile);
  } else {
    int t = threadIdx.x, lane = t & 63, wv = t >> 6;
    int tok = (b - 4608) * 4 + wv;
    const f32x4* x4 = (const f32x4*)(x + (size_t)tok * 1024);
    f32x4 xv[4];
#pragma unroll
    for (int j = 0; j < 4; ++j) xv[j] = x4[j * 64 + lane];

    unsigned short* xo = xb + (size_t)tok * 1024;
#pragma unroll
    for (int j = 0; j < 4; ++j) {
      uint2v o;
      o[0] = (unsigned)f2bf(xv[j][0]) | ((unsigned)f2bf(xv[j][1]) << 16);
      o[1] = (unsigned)f2bf(xv[j][2]) | ((unsigned)f2bf(xv[j][3]) << 16);
      *(uint2v*)(xo + j * 256 + lane * 4) = o;
    }

    float acc[NEXP];
#pragma unroll
    for (int e = 0; e < NEXP; ++e) acc[e] = 0.f;
#pragma unroll
    for (int j = 0; j < 4; ++j) {
      int base = j * 256 + lane * 4;
#pragma unroll
      for (int c = 0; c < 4; ++c) {
        float xf = xv[j][c];
        const f32x4* wp = (const f32x4*)(wr + (size_t)(base + c) * NEXP);
        f32x4 q0 = wp[0], q1 = wp[1];
#pragma unroll
        for (int e = 0; e < 4; ++e) { acc[e] += xf * q0[e]; acc[4 + e] += xf * q1[e]; }
      }
    }
#pragma unroll
    for (int off = 32; off > 0; off >>= 1) {
#pragma unroll
      for (int e = 0; e < NEXP; ++e) acc[e] += __shfl_xor(acc[e], off);
    }

    float mx = acc[0];
#pragma unroll
    for (int e = 1; e < NEXP; ++e) mx = fmaxf(mx, acc[e]);
    float s = 0.f;
#pragma unroll
    for (int e = 0; e < NEXP; ++e) s += __expf(acc[e] - mx);
    float inv = 1.f / s;

    if (lane < NEXP) probs[(size_t)tok * NEXP + lane] = __expf(acc[lane] - mx) * inv;
    if (lane == 0) {
      int i0 = 0; float v0 = acc[0];
#pragma unroll
      for (int e = 1; e < NEXP; ++e) if (acc[e] > v0) { v0 = acc[e]; i0 = e; }
      int i1 = -1; float v1 = -3.4e38f;
#pragma unroll
      for (int e = 0; e < NEXP; ++e) if (e != i0 && acc[e] > v1) { v1 = acc[e]; i1 = e; }
      rec[tok] = i0 | (i1 << 8);
      wts[2 * tok] = __expf(v0 - mx) * inv;
      wts[2 * tok + 1] = __expf(v1 - mx) * inv;
      lsebuf[tok] = mx + __logf(s);
    }
  }
}

// ---- build: SINGLE block — lists via LDS counters, ebase/tiles/counts/losses ----
__global__ __launch_bounds__(1024) void build_k(
    const int* __restrict__ rec, const float* __restrict__ wts, const float* __restrict__ probs,
    const float* __restrict__ lsebuf,
    int* __restrict__ tlist, float* __restrict__ wlist,
    int* __restrict__ counts, int* __restrict__ ebase, int* __restrict__ tiles,
    float* __restrict__ lossout) {
  __shared__ int lcnt[NEXP];
  __shared__ float sprob[NEXP];
  __shared__ float sz;
  int t = threadIdx.x, lane = t & 63;
  if (t < NEXP) { lcnt[t] = 0; sprob[t] = 0.f; }
  if (t == 0) sz = 0.f;
  __syncthreads();

  float pacc[NEXP];
#pragma unroll
  for (int e = 0; e < NEXP; ++e) pacc[e] = 0.f;
  float zacc = 0.f;

#pragma unroll
  for (int it = 0; it < 4; ++it) {
    int tok = t + it * 1024;
    int r = rec[tok];
    int i0 = r & 255, i1 = (r >> 8) & 255;
    int p0 = atomicAdd(&lcnt[i0], 1);
    tlist[i0 * NTOK + p0] = tok;
    wlist[i0 * NTOK + p0] = wts[2 * tok];
    int p1 = atomicAdd(&lcnt[i1], 1);
    tlist[i1 * NTOK + p1] = tok | (1 << 16);
    wlist[i1 * NTOK + p1] = wts[2 * tok + 1];
    f32x4 a = ((const f32x4*)(probs + (size_t)tok * NEXP))[0];
    f32x4 c = ((const f32x4*)(probs + (size_t)tok * NEXP))[1];
#pragma unroll
    for (int j = 0; j < 4; ++j) { pacc[j] += a[j]; pacc[4 + j] += c[j]; }
    float lv = lsebuf[tok];
    zacc += lv * lv;
  }
#pragma unroll
  for (int off = 32; off > 0; off >>= 1) {
#pragma unroll
    for (int e = 0; e < NEXP; ++e) pacc[e] += __shfl_xor(pacc[e], off);
    zacc += __shfl_xor(zacc, off);
  }
  if (lane == 0) {
#pragma unroll
    for (int e = 0; e < NEXP; ++e) atomicAdd(&sprob[e], pacc[e]);
    atomicAdd(&sz, zacc);
  }
  __syncthreads();

  if (t == 0) {
    int a = 0, tt = 0;
    float dot = 0.f;
    for (int e = 0; e < NEXP; ++e) {
      counts[e] = lcnt[e];
      ebase[e] = a;
      int nt = (lcnt[e] + 127) >> 7;
      for (int i = 0; i < nt; ++i) tiles[tt++] = (e << 16) | i;
      a += nt * 128;
      dot += (float)lcnt[e] * sprob[e];
    }
    ebase[NEXP] = a;
    for (int i = 0; i < 32; ++i) tiles[tt++] = (NEXP << 16) | i;
    while (tt < MAXTILES) tiles[tt++] = -1;
    lossout[0] = 6.103515625e-7f * dot;  // E*LB_W/(NUM_LAYERS*N*K)
    lossout[1] = sz * (0.001f / 4096.f);
  }
}

// ---- GEMM1: y<MAXTILES: 128x64 dual-B SwiGLU tiles; y>=MAXTILES: w2/sw2 transpose ----
__global__ __launch_bounds__(256, 3) void gemm1_k(
    const unsigned short* __restrict__ xb,
    const unsigned short* __restrict__ w1T, const unsigned short* __restrict__ w3T,
    const unsigned short* __restrict__ sw1T, const unsigned short* __restrict__ sw3T,
    unsigned short* __restrict__ hout,
    const int* __restrict__ tlist, const int* __restrict__ counts,
    const int* __restrict__ ebase, const int* __restrict__ tiles,
    const float* __restrict__ w2, const float* __restrict__ sw2,
    unsigned short* __restrict__ wTbase /* = w1T; w2T at +16M, sw2T at +26M */) {
  __shared__ unsigned short As[128 * 64], Bs1[64 * 64], Bs3[64 * 64];
  const int tid = threadIdx.x;

  if (blockIdx.y >= MAXTILES) {
    // ---- w2/sw2 transpose: 9 slices x 256 tiles ----
    int tb = (blockIdx.y - MAXTILES) * 16 + blockIdx.x;  // 0..2303
    int z = tb >> 8, rem = tb & 255;
    const float* S = (z < 8) ? w2 + (size_t)z * 1048576 : sw2;
    unsigned short* Dp = (z < 8) ? wTbase + (size_t)(16 + z) * 1048576
                                 : wTbase + (size_t)26 * 1048576;
    transpose_tile(S, Dp, (rem >> 4) * 64, (rem & 15) * 64, tid,
                   (unsigned short (*)[65])As);
    return;
  }

  int td = tiles[blockIdx.y];
  if (td < 0) return;
  const int e = td >> 16;
  const int m0 = (td & 0xFFFF) << 7;
  const int n0 = blockIdx.x * 64;
  const bool sh = (e == NEXP);
  const int n_e = sh ? NTOK : counts[e];
  const int hb = ebase[e];
  const unsigned short* B1p = sh ? sw1T : w1T + (size_t)e * 1048576;
  const unsigned short* B3p = sh ? sw3T : w3T + (size_t)e * 1048576;
  const int* listp = tlist + e * NTOK;

  const int lane = tid & 63, wv = tid >> 6;
  const int wrw = wv >> 1, wc = wv & 1, l16 = lane & 15, lq = lane >> 4;

  const unsigned short* ga[4];
#pragma unroll
  for (int i = 0; i < 4; ++i) {
    int c = tid + i * 256;
    int r = c >> 3, ks = (c & 7) ^ (r & 7);
    int ar = m0 + r;
    int rowA = sh ? ar : (ar < n_e ? (listp[ar] & 0xFFFF) : 0);
    ga[i] = xb + (size_t)rowA * 1024 + ks * 8;
  }
  const unsigned short* gb[2];
  const unsigned short* gc[2];
#pragma unroll
  for (int i = 0; i < 2; ++i) {
    int c = tid + i * 256;
    int r = c >> 3, ks = (c & 7) ^ (r & 7);
    gb[i] = B1p + (size_t)(n0 + r) * 1024 + ks * 8;
    gc[i] = B3p + (size_t)(n0 + r) * 1024 + ks * 8;
  }
  unsigned short* lA[4];
#pragma unroll
  for (int i = 0; i < 4; ++i) lA[i] = As + i * 2048 + wv * 512;
  unsigned short* lB[2] = {Bs1 + wv * 512, Bs1 + 2048 + wv * 512};
  unsigned short* lC[2] = {Bs3 + wv * 512, Bs3 + 2048 + wv * 512};

  f32x4 accg[4][2], accu[4][2];
#pragma unroll
  for (int mi = 0; mi < 4; ++mi)
#pragma unroll
    for (int ni = 0; ni < 2; ++ni)
#pragma unroll
      for (int r = 0; r < 4; ++r) { accg[mi][ni][r] = 0.f; accu[mi][ni][r] = 0.f; }

  for (int k0 = 0; k0 < 1024; k0 += 64) {
#pragma unroll
    for (int i = 0; i < 4; ++i) { gll16(ga[i], lA[i]); ga[i] += 64; }
#pragma unroll
    for (int i = 0; i < 2; ++i) { gll16(gb[i], lB[i]); gb[i] += 64; gll16(gc[i], lC[i]); gc[i] += 64; }
    __syncthreads();
#pragma unroll
    for (int kh = 0; kh < 2; ++kh) {
      short8 af[4], b1f[2], b3f[2];
#pragma unroll
      for (int mi = 0; mi < 4; ++mi) {
        int R = wrw * 64 + mi * 16 + l16;
        int s = (kh * 4 + lq) ^ (R & 7);
        af[mi] = *(const short8*)&As[R * 64 + s * 8];
      }
#pragma unroll
      for (int ni = 0; ni < 2; ++ni) {
        int R = wc * 32 + ni * 16 + l16;
        int s = (kh * 4 + lq) ^ (R & 7);
        b1f[ni] = *(const short8*)&Bs1[R * 64 + s * 8];
        b3f[ni] = *(const short8*)&Bs3[R * 64 + s * 8];
      }
#pragma unroll
      for (int mi = 0; mi < 4; ++mi)
#pragma unroll
        for (int ni = 0; ni < 2; ++ni) {
          accg[mi][ni] = __builtin_amdgcn_mfma_f32_16x16x32_bf16(af[mi], b1f[ni], accg[mi][ni], 0, 0, 0);
          accu[mi][ni] = __builtin_amdgcn_mfma_f32_16x16x32_bf16(af[mi], b3f[ni], accu[mi][ni], 0, 0, 0);
        }
    }
    __syncthreads();
  }

#pragma unroll
  for (int mi = 0; mi < 4; ++mi)
#pragma unroll
    for (int ni = 0; ni < 2; ++ni) {
      int col = n0 + wc * 32 + ni * 16 + l16;
#pragma unroll
      for (int r = 0; r < 4; ++r) {
        int row = m0 + wrw * 64 + mi * 16 + lq * 4 + r;
        float g = accg[mi][ni][r], u = accu[mi][ni][r];
        float h = g / (1.f + __expf(-g)) * u;
        hout[(size_t)(hb + row) * 1024 + col] = (row < n_e) ? f2bf(h) : (unsigned short)0;
      }
    }
}

// ---- GEMM2: 128x64 tile, BK=64; expert tiles -> ybuf[k] slices, shared tiles -> out ----
__global__ __launch_bounds__(256, 4) void gemm2_k(
    const unsigned short* __restrict__ hbuf,
    const unsigned short* __restrict__ w2T, const unsigned short* __restrict__ sw2T,
    float* __restrict__ ybuf, float* __restrict__ out,
    const int* __restrict__ tlist, const float* __restrict__ wlist,
    const int* __restrict__ counts, const int* __restrict__ ebase, const int* __restrict__ tiles) {
  int td = tiles[blockIdx.y];
  if (td < 0) return;
  const int e = td >> 16;
  const int m0 = (td & 0xFFFF) << 7;
  const int n0 = blockIdx.x * 64;
  const bool sh = (e == NEXP);
  const int n_e = sh ? NTOK : counts[e];
  const int hb = ebase[e];
  const unsigned short* Bp = sh ? sw2T : w2T + (size_t)e * 1048576;
  const int* listp = tlist + e * NTOK;

  __shared__ unsigned short As[128 * 64], Bs[64 * 64];
  const int tid = threadIdx.x, lane = tid & 63, wv = tid >> 6;
  const int wrw = wv >> 1, wc = wv & 1, l16 = lane & 15, lq = lane >> 4;

  const unsigned short* ga[4];
#pragma unroll
  for (int i = 0; i < 4; ++i) {
    int c = tid + i * 256;
    int r = c >> 3, ks = (c & 7) ^ (r & 7);
    ga[i] = hbuf + (size_t)(hb + m0 + r) * 1024 + ks * 8;  // padded rows zero-filled
  }
  const unsigned short* gb[2];
#pragma unroll
  for (int i = 0; i < 2; ++i) {
    int c = tid + i * 256;
    int r = c >> 3, ks = (c & 7) ^ (r & 7);
    gb[i] = Bp + (size_t)(n0 + r) * 1024 + ks * 8;
  }
  unsigned short* lA[4];
#pragma unroll
  for (int i = 0; i < 4; ++i) lA[i] = As + i * 2048 + wv * 512;
  unsigned short* lB[2] = {Bs + wv * 512, Bs + 2048 + wv * 512};

  f32x4 acc[4][2];
#pragma unroll
  for (int mi = 0; mi < 4; ++mi)
#pragma unroll
    for (int ni = 0; ni < 2; ++ni)
#pragma unroll
      for (int r = 0; r < 4; ++r) acc[mi][ni][r] = 0.f;

  for (int k0 = 0; k0 < 1024; k0 += 64) {
#pragma unroll
    for (int i = 0; i < 4; ++i) { gll16(ga[i], lA[i]); ga[i] += 64; }
#pragma unroll
    for (int i = 0; i < 2; ++i) { gll16(gb[i], lB[i]); gb[i] += 64; }
    __syncthreads();
#pragma unroll
    for (int kh = 0; kh < 2; ++kh) {
      short8 af[4], bf[2];
#pragma unroll
      for (int mi = 0; mi < 4; ++mi) {
        int R = wrw * 64 + mi * 16 + l16;
        int s = (kh * 4 + lq) ^ (R & 7);
        af[mi] = *(const short8*)&As[R * 64 + s * 8];
      }
#pragma unroll
      for (int ni = 0; ni < 2; ++ni) {
        int R = wc * 32 + ni * 16 + l16;
        int s = (kh * 4 + lq) ^ (R & 7);
        bf[ni] = *(const short8*)&Bs[R * 64 + s * 8];
      }
#pragma unroll
      for (int mi = 0; mi < 4; ++mi)
#pragma unroll
        for (int ni = 0; ni < 2; ++ni)
          acc[mi][ni] = __builtin_amdgcn_mfma_f32_16x16x32_bf16(af[mi], bf[ni], acc[mi][ni], 0, 0, 0);
    }
    __syncthreads();
  }

#pragma unroll
  for (int mi = 0; mi < 4; ++mi)
#pragma unroll
    for (int r = 0; r < 4; ++r) {
      int row = m0 + wrw * 64 + mi * 16 + lq * 4 + r;
      int col = n0 + wc * 32 + l16;
      if (sh) {
        float* yp = out + (size_t)row * 1024 + col;
#pragma unroll
        for (int ni = 0; ni < 2; ++ni) yp[ni * 16] = acc[mi][ni][r] * (1.f / 3.f);
      } else if (row < n_e) {
        int ent = listp[row];
        float wt = wlist[e * NTOK + row] * (2.f / 3.f);
        int tok = ent & 0xFFFF, ks = ent >> 16;
        float* yp = ybuf + ((size_t)ks * NTOK + tok) * 1024 + col;
#pragma unroll
        for (int ni = 0; ni < 2; ++ni) yp[ni * 16] = wt * acc[mi][ni][r];
      }
    }
}

// ---- combine: out += y0 + y1 (shared part already in out; scales folded) ----
__global__ __launch_bounds__(256) void combine_k(const float* __restrict__ y,
                                                 float* __restrict__ out) {
  size_t i = (size_t)blockIdx.x * 256 + threadIdx.x;
  const f32x4* y0 = (const f32x4*)y + i;
  const f32x4* y1 = y0 + (NTOK * 1024 / 4);
  f32x4 o = ((f32x4*)out)[i];
  ((f32x4*)out)[i] = o + *y0 + *y1;
}

extern "C" void kernel_launch(void* const* d_in, const int* in_sizes, int n_in,
                              void* d_out, int out_size, void* d_ws, size_t ws_size,
                              hipStream_t stream) {
  const float* x   = (const float*)d_in[0];
  const float* wrt = (const float*)d_in[1];
  const float* w1  = (const float*)d_in[2];
  const float* w3  = (const float*)d_in[3];
  const float* w2  = (const float*)d_in[4];
  const float* sw1 = (const float*)d_in[5];
  const float* sw3 = (const float*)d_in[6];
  const float* sw2 = (const float*)d_in[7];
  float* out = (float*)d_out;

  char* p = (char*)d_ws;
  auto alloc = [&](size_t b) { char* r = p; p += (b + 255) & ~(size_t)255; return r; };
  unsigned short* xb   = (unsigned short*)alloc((size_t)NTOK * 1024 * 2);
  // contiguous: w1T(8) w3T(8) w2T(8) sw1T sw3T sw2T = 27 x 1M elems
  unsigned short* w1T  = (unsigned short*)alloc((size_t)27 * 1048576 * 2);
  unsigned short* w3T  = w1T + (size_t)8 * 1048576;
  unsigned short* w2T  = w3T + (size_t)8 * 1048576;
  unsigned short* sw1T = w2T + (size_t)8 * 1048576;
  unsigned short* sw3T = sw1T + 1048576;
  unsigned short* sw2T = sw3T + 1048576;
  unsigned short* hbuf = (unsigned short*)alloc((size_t)13312 * 1024 * 2);
  float* ybuf   = (float*)alloc((size_t)2 * NTOK * 1024 * 4);
  int* tlist    = (int*)alloc((size_t)NEXP * NTOK * 4);
  float* wlist  = (float*)alloc((size_t)NEXP * NTOK * 4);
  int* rec      = (int*)alloc((size_t)NTOK * 4);
  float* wts    = (float*)alloc((size_t)NTOK * 2 * 4);
  float* probs  = (float*)alloc((size_t)NTOK * NEXP * 4);
  float* lsebuf = (float*)alloc((size_t)NTOK * 4);
  int* tiles    = (int*)alloc(MAXTILES * 4);
  int* ebase    = (int*)alloc(256);
  int* counts   = (int*)alloc(256);

  prep_k<<<5632, 256, 0, stream>>>(w1, w3, sw1, sw3, w1T,
                                   x, wrt, xb, rec, wts, probs, lsebuf);
  build_k<<<1, 1024, 0, stream>>>(rec, wts, probs, lsebuf, tlist, wlist,
                                  counts, ebase, tiles, out + (size_t)NTOK * 1024);
  gemm1_k<<<dim3(16, MAXTILES + 144), 256, 0, stream>>>(
      xb, w1T, w3T, sw1T, sw3T, hbuf, tlist, counts, ebase, tiles, w2, sw2, w1T);
  gemm2_k<<<dim3(16, MAXTILES), 256, 0, stream>>>(hbuf, w2T, sw2T, ybuf, out,
                                                  tlist, wlist, counts, ebase, tiles);
  combine_k<<<NTOK * 1024 / 4 / 256, 256, 0, stream>>>(ybuf, out);
}